// Round 2
// baseline (391.486 us; speedup 1.0000x reference)
//
#include <hip/hip_runtime.h>
#include <cstdint>
#include <cstddef>

typedef float  v4f __attribute__((ext_vector_type(4)));
typedef short  v8s __attribute__((ext_vector_type(8)));
typedef int    v4i __attribute__((ext_vector_type(4)));
typedef unsigned int v2u __attribute__((ext_vector_type(2)));

#define BB 8
#define NN 2048
#define DD 128
#define TI 16
#define NEGV (-9e15f)

__device__ __forceinline__ unsigned short f2bf(float x) {
  unsigned u = __float_as_uint(x);
  u = u + 0x7FFFu + ((u >> 16) & 1u);   // round-to-nearest-even
  return (unsigned short)(u >> 16);
}

// K1: Wh = h @ W (fp32), Wh1 = Wh·a[:128], Wh2 = Wh·a[128:], and WhbT = bf16(Wh)^T per batch.
// One block per (b, 16-row tile) -> 1024 blocks (4/CU). 256 threads:
// c = tid&31 -> cols 4c..4c+3, g = tid>>5 -> rows 2g..2g+1.
__global__ __launch_bounds__(256) void gat_k1(
    const float* __restrict__ h, const float* __restrict__ W, const float* __restrict__ a,
    short* __restrict__ whbT, float* __restrict__ wh1g, float* __restrict__ wh2g)
{
  __shared__ __align__(16) float hs[TI * DD];                 // 8 KB
  __shared__ __align__(16) unsigned short staging[DD * 24];   // 6 KB (stride 24 shorts = 48B, 16B-aligned)

  const int tid = threadIdx.x;
  const int b = blockIdx.y;
  const int i0 = blockIdx.x * TI;

  // load h tile (16 x 128 fp32), coalesced float4
  const v4f* hg = (const v4f*)(h + (size_t)(b * NN + i0) * DD);
  ((v4f*)hs)[tid] = hg[tid];
  ((v4f*)hs)[tid + 256] = hg[tid + 256];
  __syncthreads();

  const int c = tid & 31;
  const int g = tid >> 5;
  const v4f* Wg4 = (const v4f*)W;

  v4f acc[2];
  #pragma unroll
  for (int r = 0; r < 2; r++) acc[r] = (v4f){0.f, 0.f, 0.f, 0.f};

  for (int k0 = 0; k0 < DD; k0 += 4) {
    v4f w0 = Wg4[(k0 + 0) * 32 + c];
    v4f w1 = Wg4[(k0 + 1) * 32 + c];
    v4f w2 = Wg4[(k0 + 2) * 32 + c];
    v4f w3 = Wg4[(k0 + 3) * 32 + c];
    #pragma unroll
    for (int r = 0; r < 2; r++) {
      v4f hv = *(const v4f*)&hs[(g * 2 + r) * DD + k0];
      acc[r] += hv.x * w0 + hv.y * w1 + hv.z * w2 + hv.w * w3;
    }
  }

  // Wh1/Wh2 partial dot with a, reduce across the 32 threads (c) sharing a row group
  v4f a1 = ((const v4f*)a)[c];
  v4f a2 = ((const v4f*)a)[32 + c];
  #pragma unroll
  for (int r = 0; r < 2; r++) {
    float p1 = acc[r].x * a1.x + acc[r].y * a1.y + acc[r].z * a1.z + acc[r].w * a1.w;
    float p2 = acc[r].x * a2.x + acc[r].y * a2.y + acc[r].z * a2.z + acc[r].w * a2.w;
    #pragma unroll
    for (int off = 16; off > 0; off >>= 1) {
      p1 += __shfl_xor(p1, off);
      p2 += __shfl_xor(p2, off);
    }
    if (c == 0) {
      wh1g[b * NN + i0 + g * 2 + r] = p1;
      wh2g[b * NN + i0 + g * 2 + r] = p2;
    }
    #pragma unroll
    for (int cc = 0; cc < 4; cc++)
      staging[(c * 4 + cc) * 24 + g * 2 + r] = f2bf(acc[r][cc]);
  }
  __syncthreads();

  // write WhbT[b][t][i0..i0+15] (16B per lane; 128 t-rows x 2 v8s = 256 stores)
  {
    int t = tid >> 1;
    int i8 = tid & 1;
    v8s val = *(const v8s*)&staging[t * 24 + i8 * 8];
    *(v8s*)(whbT + (size_t)b * DD * NN + (size_t)t * NN + i0 + i8 * 8) = val;
  }
}

// K2: fused masked-softmax (write attention) + h' = att @ Wh via bf16 MFMA + residual.
// One block per (b, 16-row tile) -> 1024 blocks (4/CU). 256 threads = 4 waves.
// Waves partition the d dimension (2 d-tiles of 16 each).
__global__ __launch_bounds__(256) void gat_k2(
    const float* __restrict__ h, const int* __restrict__ adj,
    const short* __restrict__ whbT, const float* __restrict__ wh1g,
    const float* __restrict__ wh2g, float* __restrict__ out,
    float* __restrict__ attout)
{
  __shared__ __align__(16) float wh2s[NN];                 // 8 KB
  __shared__ float wh1s[TI];
  __shared__ unsigned int maskw[TI * 64];                  // 4 KB adj bitmask
  __shared__ float m_s[TI];
  __shared__ float rs_s[TI];
  __shared__ __align__(16) unsigned short atile[2][TI * 72];  // double-buffered, 2 x 2.25 KB

  const int tid = threadIdx.x;
  const int lane = tid & 63;
  const int wid = tid >> 6;
  const int b = blockIdx.y;
  const int i0 = blockIdx.x * TI;

  {
    const v4f* w2g4 = (const v4f*)(wh2g + (size_t)b * NN);
    ((v4f*)wh2s)[tid] = w2g4[tid];
    ((v4f*)wh2s)[tid + 256] = w2g4[tid + 256];
  }
  if (tid < TI) wh1s[tid] = wh1g[b * NN + i0 + tid];
  __syncthreads();

  // ---- Phase 1: adj read (once), row max & sum, mask bitpack. Wave w owns rows w, w+4, ...
  for (int ii = wid; ii < TI; ii += 4) {
    const v4i* arow = (const v4i*)(adj + (size_t)(b * NN + i0 + ii) * NN);
    const float wh1v = wh1s[ii];
    float e[32];
    float m = -INFINITY;
    unsigned mbits = 0u;
    #pragma unroll
    for (int u = 0; u < 8; u++) {
      v4i av = __builtin_nontemporal_load(&arow[u * 64 + lane]);
      v4f w2v = ((const v4f*)wh2s)[u * 64 + lane];
      #pragma unroll
      for (int q = 0; q < 4; q++) {
        bool mk = av[q] > 0;
        float x = wh1v + w2v[q];
        float ev = mk ? (x > 0.f ? x : 0.2f * x) : NEGV;
        e[u * 4 + q] = ev;
        m = fmaxf(m, ev);
        mbits |= (mk ? 1u : 0u) << (u * 4 + q);
      }
    }
    maskw[ii * 64 + lane] = mbits;
    #pragma unroll
    for (int off = 32; off > 0; off >>= 1) m = fmaxf(m, __shfl_xor(m, off));
    float s = 0.f;
    #pragma unroll
    for (int k = 0; k < 32; k++) s += __expf(e[k] - m);
    #pragma unroll
    for (int off = 32; off > 0; off >>= 1) s += __shfl_xor(s, off);
    if (lane == 0) { m_s[ii] = m; rs_s[ii] = 1.f / s; }
  }
  __syncthreads();

  // ---- Phase 2: per 64-wide j chunk: att (fp32 NT write + bf16 LDS) then MFMA accumulate.
  // Thread -> att element mapping: i = tid>>4 (row), jq = tid&15 (4-col group). One float4 each.
  float* attrow_base = attout + (size_t)(b * NN + i0) * NN;
  const short* whbT_b = whbT + (size_t)b * DD * NN;
  const int m16 = lane & 15;
  const int quad = lane >> 4;
  const int irow = tid >> 4;
  const int jq = tid & 15;
  const float wh1v = wh1s[irow];
  const float mi_r = m_s[irow];
  const float rsi_r = rs_s[irow];

  v4f acc[2];
  acc[0] = (v4f){0.f, 0.f, 0.f, 0.f};
  acc[1] = (v4f){0.f, 0.f, 0.f, 0.f};

  for (int jc = 0; jc < 32; jc++) {
    const int j0 = jc * 64;
    const int ubit = (jc >> 2) << 2;   // = (j>>8)*4, constant within chunk
    unsigned short* buf = atile[jc & 1];

    // attention for this chunk: one float4 group per thread
    {
      unsigned mw = maskw[irow * 64 + ((jc * 16 + jq) & 63)];
      v4f w2v = ((const v4f*)wh2s)[(j0 >> 2) + jq];
      v4f av;
      unsigned short ab[4];
      #pragma unroll
      for (int q = 0; q < 4; q++) {
        float x = wh1v + w2v[q];
        float ev = ((mw >> (ubit + q)) & 1u) ? (x > 0.f ? x : 0.2f * x) : NEGV;
        float at = __expf(ev - mi_r) * rsi_r;
        av[q] = at;
        ab[q] = f2bf(at);
      }
      __builtin_nontemporal_store(av, (v4f*)(attrow_base + (size_t)irow * NN + j0 + jq * 4));
      v2u uv;
      uv[0] = (unsigned)ab[0] | ((unsigned)ab[1] << 16);
      uv[1] = (unsigned)ab[2] | ((unsigned)ab[3] << 16);
      *(v2u*)&buf[irow * 72 + jq * 4] = uv;
    }

    // prefetch B fragments (independent of atile) before the barrier
    v8s bfr[2][2];
    #pragma unroll
    for (int ks = 0; ks < 2; ks++)
      #pragma unroll
      for (int t = 0; t < 2; t++)
        bfr[ks][t] = *(const v8s*)(whbT_b + (size_t)((wid * 2 + t) * 16 + m16) * NN
                                   + j0 + ks * 32 + quad * 8);

    __syncthreads();

    // MFMA: all waves use rows 0..15 (A), wave's own 2 d-tiles (B). K=64 (2 steps of 32).
    #pragma unroll
    for (int ks = 0; ks < 2; ks++) {
      v8s af = *(const v8s*)&buf[m16 * 72 + ks * 32 + quad * 8];
      acc[0] = __builtin_amdgcn_mfma_f32_16x16x32_bf16(af, bfr[ks][0], acc[0], 0, 0, 0);
      acc[1] = __builtin_amdgcn_mfma_f32_16x16x32_bf16(af, bfr[ks][1], acc[1], 0, 0, 0);
    }
    // single barrier per chunk is safe with double buffering: writers of buf[p] at chunk
    // jc+2 are separated from readers at chunk jc by the barrier at chunk jc+1.
  }

  // ---- Epilogue: out = h + h'. C/D layout: col = lane&15, row = quad*4 + reg.
  #pragma unroll
  for (int t = 0; t < 2; t++) {
    #pragma unroll
    for (int r = 0; r < 4; r++) {
      size_t gidx = ((size_t)(b * NN + i0 + quad * 4 + r)) * DD + (wid * 2 + t) * 16 + m16;
      out[gidx] = h[gidx] + acc[t][r];
    }
  }
}

extern "C" void kernel_launch(void* const* d_in, const int* in_sizes, int n_in,
                              void* d_out, int out_size, void* d_ws, size_t ws_size,
                              hipStream_t stream) {
  const float* h  = (const float*)d_in[0];
  const int* adj  = (const int*)d_in[1];
  const float* W  = (const float*)d_in[2];
  const float* a  = (const float*)d_in[3];

  float* out    = (float*)d_out;
  float* attout = out + (size_t)BB * NN * DD;

  short* whbT = (short*)d_ws;                                    // 4 MB bf16 Wh^T per batch
  float* wh1  = (float*)((char*)d_ws + (size_t)BB * DD * NN * 2);
  float* wh2  = wh1 + BB * NN;

  gat_k1<<<dim3(NN / TI, BB), 256, 0, stream>>>(h, W, a, whbT, wh1, wh2);
  gat_k2<<<dim3(NN / TI, BB), 256, 0, stream>>>(h, adj, whbT, wh1, wh2, out, attout);
}

// Round 3
// 285.886 us; speedup vs baseline: 1.3694x; 1.3694x over previous
//
#include <hip/hip_runtime.h>
#include <cstdint>
#include <cstddef>

typedef float  v4f __attribute__((ext_vector_type(4)));
typedef short  v8s __attribute__((ext_vector_type(8)));
typedef int    v4i __attribute__((ext_vector_type(4)));
typedef unsigned int v2u __attribute__((ext_vector_type(2)));

#define BB 8
#define NN 2048
#define DD 128
#define TI 16
#define NEGV (-9e15f)

__device__ __forceinline__ unsigned short f2bf(float x) {
  unsigned u = __float_as_uint(x);
  u = u + 0x7FFFu + ((u >> 16) & 1u);   // round-to-nearest-even
  return (unsigned short)(u >> 16);
}

// ---------------------------------------------------------------------------
// K1 (MFMA): Wh = h @ W, Wh1 = Wh·a[:128], Wh2 = Wh·a[128:], whbT = bf16(Wh)^T.
// Block = 64 rows of h (4 waves x 16 rows), grid = (2048/64, B) = 256 blocks.
// W is transposed to bf16 in LDS once per block; A-frags come straight from
// global h (fp32 -> bf16). C stays fp32 for the Wh1/Wh2 dot (feeds exp).
// ---------------------------------------------------------------------------
__global__ __launch_bounds__(256) void gat_k1(
    const float* __restrict__ h, const float* __restrict__ W, const float* __restrict__ a,
    short* __restrict__ whbT, float* __restrict__ wh1g, float* __restrict__ wh2g)
{
  __shared__ __align__(16) unsigned short wT[DD * 136];      // W^T bf16, pad 8 -> 34 KB
  __shared__ __align__(16) unsigned short staging[DD * 72];  // c x i transpose, pad 8 -> 18 KB

  const int tid  = threadIdx.x;
  const int lane = tid & 63;
  const int wid  = tid >> 6;
  const int m16  = lane & 15;
  const int quad = lane >> 4;
  const int b    = blockIdx.y;
  const int i0   = blockIdx.x * 64;

  // ---- stage W^T (bf16) in LDS. W row-major [k][c]; wT[c][k].
  {
    const v4f* W4 = (const v4f*)W;
    #pragma unroll
    for (int it = 0; it < 16; it++) {
      int idx = it * 256 + tid;          // 4096 float4
      int k  = idx >> 5;
      int c4 = (idx & 31) * 4;
      v4f wv = W4[idx];
      #pragma unroll
      for (int q = 0; q < 4; q++)
        wT[(c4 + q) * 136 + k] = f2bf(wv[q]);
    }
  }

  // ---- A fragments from global h (row i0 + wid*16 + m16), 4 k-steps x 8 floats
  const float* hrow = h + (size_t)(b * NN + i0 + wid * 16 + m16) * DD;
  v8s af[4];
  #pragma unroll
  for (int ks = 0; ks < 4; ks++) {
    v4f x0 = *(const v4f*)(hrow + ks * 32 + quad * 8);
    v4f x1 = *(const v4f*)(hrow + ks * 32 + quad * 8 + 4);
    v8s t;
    t[0] = (short)f2bf(x0.x); t[1] = (short)f2bf(x0.y);
    t[2] = (short)f2bf(x0.z); t[3] = (short)f2bf(x0.w);
    t[4] = (short)f2bf(x1.x); t[5] = (short)f2bf(x1.y);
    t[6] = (short)f2bf(x1.z); t[7] = (short)f2bf(x1.w);
    af[ks] = t;
  }
  __syncthreads();

  // ---- MFMA: 8 n-tiles x 4 k-steps
  v4f acc[8];
  #pragma unroll
  for (int t = 0; t < 8; t++) acc[t] = (v4f){0.f, 0.f, 0.f, 0.f};

  #pragma unroll
  for (int ks = 0; ks < 4; ks++) {
    #pragma unroll
    for (int t = 0; t < 8; t++) {
      v8s bf = *(const v8s*)&wT[(t * 16 + m16) * 136 + ks * 32 + quad * 8];
      acc[t] = __builtin_amdgcn_mfma_f32_16x16x32_bf16(af[ks], bf, acc[t], 0, 0, 0);
    }
  }

  // ---- Wh1/Wh2 from fp32 accumulators. Lane owns cols {t*16+m16}, rows quad*4+r.
  {
    float a1v[8], a2v[8];
    #pragma unroll
    for (int t = 0; t < 8; t++) {
      a1v[t] = a[t * 16 + m16];
      a2v[t] = a[DD + t * 16 + m16];
    }
    #pragma unroll
    for (int r = 0; r < 4; r++) {
      float p1 = 0.f, p2 = 0.f;
      #pragma unroll
      for (int t = 0; t < 8; t++) {
        p1 += acc[t][r] * a1v[t];
        p2 += acc[t][r] * a2v[t];
      }
      #pragma unroll
      for (int off = 8; off > 0; off >>= 1) {   // reduce across the 16 lanes of a quad
        p1 += __shfl_xor(p1, off);
        p2 += __shfl_xor(p2, off);
      }
      if (m16 == 0) {
        int gi = b * NN + i0 + wid * 16 + quad * 4 + r;
        wh1g[gi] = p1;
        wh2g[gi] = p2;
      }
    }
  }

  // ---- transpose C tile (c x i) in LDS, then coalesced bf16 stores to whbT
  #pragma unroll
  for (int t = 0; t < 8; t++)
    #pragma unroll
    for (int r = 0; r < 4; r++)
      staging[(t * 16 + m16) * 72 + wid * 16 + quad * 4 + r] = f2bf(acc[t][r]);
  __syncthreads();

  #pragma unroll
  for (int it = 0; it < 4; it++) {
    int idx = it * 256 + tid;            // 1024 v8s = 128 c x 8 groups of 8 i
    int c  = idx >> 3;
    int i8 = idx & 7;
    v8s val = *(const v8s*)&staging[c * 72 + i8 * 8];
    *(v8s*)(whbT + (size_t)b * DD * NN + (size_t)c * NN + i0 + i8 * 8) = val;
  }
}

// ---------------------------------------------------------------------------
// K2: fused masked-softmax (write attention) + h' = att @ Wh via bf16 MFMA + residual.
// One block per (b, 16-row tile) -> 1024 blocks (4/CU). 256 threads = 4 waves.
// Waves partition the d dimension (2 d-tiles of 16 each).
// ---------------------------------------------------------------------------
__global__ __launch_bounds__(256) void gat_k2(
    const float* __restrict__ h, const int* __restrict__ adj,
    const short* __restrict__ whbT, const float* __restrict__ wh1g,
    const float* __restrict__ wh2g, float* __restrict__ out,
    float* __restrict__ attout)
{
  __shared__ __align__(16) float wh2s[NN];                 // 8 KB
  __shared__ float wh1s[TI];
  __shared__ unsigned int maskw[TI * 64];                  // 4 KB adj bitmask
  __shared__ float m_s[TI];
  __shared__ float rs_s[TI];
  __shared__ __align__(16) unsigned short atile[2][TI * 72];  // double-buffered

  const int tid = threadIdx.x;
  const int lane = tid & 63;
  const int wid = tid >> 6;
  const int b = blockIdx.y;
  const int i0 = blockIdx.x * TI;

  {
    const v4f* w2g4 = (const v4f*)(wh2g + (size_t)b * NN);
    ((v4f*)wh2s)[tid] = w2g4[tid];
    ((v4f*)wh2s)[tid + 256] = w2g4[tid + 256];
  }
  if (tid < TI) wh1s[tid] = wh1g[b * NN + i0 + tid];
  __syncthreads();

  // ---- Phase 1: adj read (once), row max & sum, mask bitpack. Wave w owns rows w, w+4, ...
  for (int ii = wid; ii < TI; ii += 4) {
    const v4i* arow = (const v4i*)(adj + (size_t)(b * NN + i0 + ii) * NN);
    const float wh1v = wh1s[ii];
    float e[32];
    float m = -INFINITY;
    unsigned mbits = 0u;
    #pragma unroll
    for (int u = 0; u < 8; u++) {
      v4i av = __builtin_nontemporal_load(&arow[u * 64 + lane]);
      v4f w2v = ((const v4f*)wh2s)[u * 64 + lane];
      #pragma unroll
      for (int q = 0; q < 4; q++) {
        bool mk = av[q] > 0;
        float x = wh1v + w2v[q];
        float ev = mk ? (x > 0.f ? x : 0.2f * x) : NEGV;
        e[u * 4 + q] = ev;
        m = fmaxf(m, ev);
        mbits |= (mk ? 1u : 0u) << (u * 4 + q);
      }
    }
    maskw[ii * 64 + lane] = mbits;
    #pragma unroll
    for (int off = 32; off > 0; off >>= 1) m = fmaxf(m, __shfl_xor(m, off));
    float s = 0.f;
    #pragma unroll
    for (int k = 0; k < 32; k++) s += __expf(e[k] - m);
    #pragma unroll
    for (int off = 32; off > 0; off >>= 1) s += __shfl_xor(s, off);
    if (lane == 0) { m_s[ii] = m; rs_s[ii] = 1.f / s; }
  }
  __syncthreads();

  // ---- Phase 2: per 64-wide j chunk: att (fp32 NT write + bf16 LDS) then MFMA accumulate.
  float* attrow_base = attout + (size_t)(b * NN + i0) * NN;
  const short* whbT_b = whbT + (size_t)b * DD * NN;
  const int m16 = lane & 15;
  const int quad = lane >> 4;
  const int irow = tid >> 4;
  const int jq = tid & 15;
  const float wh1v = wh1s[irow];
  const float mi_r = m_s[irow];
  const float rsi_r = rs_s[irow];

  v4f acc[2];
  acc[0] = (v4f){0.f, 0.f, 0.f, 0.f};
  acc[1] = (v4f){0.f, 0.f, 0.f, 0.f};

  for (int jc = 0; jc < 32; jc++) {
    const int j0 = jc * 64;
    const int ubit = (jc >> 2) << 2;   // = (j>>8)*4, constant within chunk
    unsigned short* buf = atile[jc & 1];

    // attention for this chunk: one float4 group per thread
    {
      unsigned mw = maskw[irow * 64 + ((jc * 16 + jq) & 63)];
      v4f w2v = ((const v4f*)wh2s)[(j0 >> 2) + jq];
      v4f av;
      unsigned short ab[4];
      #pragma unroll
      for (int q = 0; q < 4; q++) {
        float x = wh1v + w2v[q];
        float ev = ((mw >> (ubit + q)) & 1u) ? (x > 0.f ? x : 0.2f * x) : NEGV;
        float at = __expf(ev - mi_r) * rsi_r;
        av[q] = at;
        ab[q] = f2bf(at);
      }
      __builtin_nontemporal_store(av, (v4f*)(attrow_base + (size_t)irow * NN + j0 + jq * 4));
      v2u uv;
      uv[0] = (unsigned)ab[0] | ((unsigned)ab[1] << 16);
      uv[1] = (unsigned)ab[2] | ((unsigned)ab[3] << 16);
      *(v2u*)&buf[irow * 72 + jq * 4] = uv;
    }

    // prefetch B fragments (independent of atile) before the barrier
    v8s bfr[2][2];
    #pragma unroll
    for (int ks = 0; ks < 2; ks++)
      #pragma unroll
      for (int t = 0; t < 2; t++)
        bfr[ks][t] = *(const v8s*)(whbT_b + (size_t)((wid * 2 + t) * 16 + m16) * NN
                                   + j0 + ks * 32 + quad * 8);

    __syncthreads();

    // MFMA: all waves use rows 0..15 (A), wave's own 2 d-tiles (B). K=64 (2 steps of 32).
    #pragma unroll
    for (int ks = 0; ks < 2; ks++) {
      v8s af = *(const v8s*)&buf[m16 * 72 + ks * 32 + quad * 8];
      acc[0] = __builtin_amdgcn_mfma_f32_16x16x32_bf16(af, bfr[ks][0], acc[0], 0, 0, 0);
      acc[1] = __builtin_amdgcn_mfma_f32_16x16x32_bf16(af, bfr[ks][1], acc[1], 0, 0, 0);
    }
    // single barrier per chunk is safe with double buffering: writers of buf[p] at chunk
    // jc+2 are separated from readers at chunk jc by the barrier at chunk jc+1.
  }

  // ---- Epilogue: out = h + h'. C/D layout: col = lane&15, row = quad*4 + reg.
  #pragma unroll
  for (int t = 0; t < 2; t++) {
    #pragma unroll
    for (int r = 0; r < 4; r++) {
      size_t gidx = ((size_t)(b * NN + i0 + quad * 4 + r)) * DD + (wid * 2 + t) * 16 + m16;
      out[gidx] = h[gidx] + acc[t][r];
    }
  }
}

extern "C" void kernel_launch(void* const* d_in, const int* in_sizes, int n_in,
                              void* d_out, int out_size, void* d_ws, size_t ws_size,
                              hipStream_t stream) {
  const float* h  = (const float*)d_in[0];
  const int* adj  = (const int*)d_in[1];
  const float* W  = (const float*)d_in[2];
  const float* a  = (const float*)d_in[3];

  float* out    = (float*)d_out;
  float* attout = out + (size_t)BB * NN * DD;

  short* whbT = (short*)d_ws;                                    // 8.4 MB bf16 Wh^T
  float* wh1  = (float*)((char*)d_ws + (size_t)BB * DD * NN * 2);
  float* wh2  = wh1 + BB * NN;

  gat_k1<<<dim3(NN / 64, BB), 256, 0, stream>>>(h, W, a, whbT, wh1, wh2);
  gat_k2<<<dim3(NN / TI, BB), 256, 0, stream>>>(h, adj, whbT, wh1, wh2, out, attout);
}